// Round 13
// baseline (48.898 us; speedup 1.0000x reference)
//
#include <hip/hip_runtime.h>
#include <hip/hip_bf16.h>
#include <math.h>

#define BATCH 256
#define DM    768
#define REPR  1024
#define FF    3072

typedef __attribute__((ext_vector_type(8))) short bf16x8;
typedef __attribute__((ext_vector_type(4))) float f32x4;

__device__ __forceinline__ unsigned bf16rne(float f){
  union{float f; unsigned u;} x; x.f = f;
  return (x.u + 0x7FFFu + ((x.u >> 16) & 1u)) >> 16;
}
__device__ __forceinline__ unsigned pk2(float lo, float hi){
  return bf16rne(lo) | (bf16rne(hi) << 16);
}

// ---------------------------------------------------------------------------
// K1 gemm_g1: G1 split-4: P1[z] = im @ Wv2 K-slices, B direct from f32 Wv2.
// Depth-2 prefetch (two named buffer sets, loads t+2/t+3 issued before the
// MFMAs of t/t+1 -> ~2 steps of latency cover; r12 was depth-1).
// ---------------------------------------------------------------------------
__global__ __launch_bounds__(256)
void gemm_g1(const float* __restrict__ Wv2, const float* __restrict__ im,
             float* __restrict__ P1)
{
  const int z = blockIdx.z, bx = blockIdx.x, by = blockIdx.y;
  const int tid = threadIdx.x;
  const int lane = tid & 63, wid = tid >> 6;
  const int wr = wid >> 1, wc = wid & 1;
  const int arow = by * 32 + wr * 16 + (lane & 15);
  const int colb = bx * 64 + wc * 32;
  const int kq8  = (lane >> 4) * 8;
  const int kb   = z * 256;              // 8 K-steps per slice

  const float* apf  = im + (size_t)arow * REPR + kb + kq8;
  const int c0 = colb + (lane & 15), c1 = c0 + 16;
  const float* wrow = Wv2 + (size_t)(kb + kq8) * DM;

  f32x4 acc0 = (f32x4)(0.0f), acc1 = (f32x4)(0.0f);

  float4 a0A, a1A, a0B, a1B;
  float b0A[8], b1A[8], b0B[8], b1B[8];
  a0A = *(const float4*)apf;        a1A = *(const float4*)(apf + 4);
  a0B = *(const float4*)(apf + 32); a1B = *(const float4*)(apf + 36);
  {
    const float* w1r = wrow + (size_t)32 * DM;
    #pragma unroll
    for (int j = 0; j < 8; ++j) {
      b0A[j] = wrow[(size_t)j * DM + c0];
      b1A[j] = wrow[(size_t)j * DM + c1];
      b0B[j] = w1r[(size_t)j * DM + c0];
      b1B[j] = w1r[(size_t)j * DM + c1];
    }
  }

  for (int s = 0; s < 8; s += 2) {
    float4 a0n, a1n, a0m, a1m;
    float b0n[8], b1n[8], b0m[8], b1m[8];
    const bool m2 = (s + 2) < 8, m3 = (s + 3) < 8;
    if (m2) {                            // prefetch t+2
      const float* a2 = apf + (s + 2) * 32;
      a0n = *(const float4*)a2; a1n = *(const float4*)(a2 + 4);
      const float* w2r = wrow + (size_t)(s + 2) * 32 * DM;
      #pragma unroll
      for (int j = 0; j < 8; ++j) {
        b0n[j] = w2r[(size_t)j * DM + c0];
        b1n[j] = w2r[(size_t)j * DM + c1];
      }
    }
    if (m3) {                            // prefetch t+3
      const float* a3 = apf + (s + 3) * 32;
      a0m = *(const float4*)a3; a1m = *(const float4*)(a3 + 4);
      const float* w3r = wrow + (size_t)(s + 3) * 32 * DM;
      #pragma unroll
      for (int j = 0; j < 8; ++j) {
        b0m[j] = w3r[(size_t)j * DM + c0];
        b1m[j] = w3r[(size_t)j * DM + c1];
      }
    }
    union U { unsigned u[4]; bf16x8 v; } afr, bfr0, bfr1;
    // step s (set A)
    afr.u[0] = pk2(a0A.x, a0A.y); afr.u[1] = pk2(a0A.z, a0A.w);
    afr.u[2] = pk2(a1A.x, a1A.y); afr.u[3] = pk2(a1A.z, a1A.w);
    #pragma unroll
    for (int j = 0; j < 4; ++j) {
      bfr0.u[j] = pk2(b0A[2*j], b0A[2*j+1]);
      bfr1.u[j] = pk2(b1A[2*j], b1A[2*j+1]);
    }
    acc0 = __builtin_amdgcn_mfma_f32_16x16x32_bf16(afr.v, bfr0.v, acc0, 0, 0, 0);
    acc1 = __builtin_amdgcn_mfma_f32_16x16x32_bf16(afr.v, bfr1.v, acc1, 0, 0, 0);
    // step s+1 (set B)
    afr.u[0] = pk2(a0B.x, a0B.y); afr.u[1] = pk2(a0B.z, a0B.w);
    afr.u[2] = pk2(a1B.x, a1B.y); afr.u[3] = pk2(a1B.z, a1B.w);
    #pragma unroll
    for (int j = 0; j < 4; ++j) {
      bfr0.u[j] = pk2(b0B[2*j], b0B[2*j+1]);
      bfr1.u[j] = pk2(b1B[2*j], b1B[2*j+1]);
    }
    acc0 = __builtin_amdgcn_mfma_f32_16x16x32_bf16(afr.v, bfr0.v, acc0, 0, 0, 0);
    acc1 = __builtin_amdgcn_mfma_f32_16x16x32_bf16(afr.v, bfr1.v, acc1, 0, 0, 0);
    if (m2) {
      a0A = a0n; a1A = a1n;
      #pragma unroll
      for (int j = 0; j < 8; ++j) { b0A[j] = b0n[j]; b1A[j] = b1n[j]; }
    }
    if (m3) {
      a0B = a0m; a1B = a1m;
      #pragma unroll
      for (int j = 0; j < 8; ++j) { b0B[j] = b0m[j]; b1B[j] = b1m[j]; }
    }
  }

  const int crow = by * 32 + wr * 16 + (lane >> 4) * 4;
  float* dst = P1 + (size_t)z * BATCH * DM;
  #pragma unroll
  for (int nf = 0; nf < 2; ++nf) {
    const int c = colb + nf * 16 + (lane & 15);
    const f32x4 a = nf ? acc1 : acc0;
    #pragma unroll
    for (int r = 0; r < 4; ++r)
      dst[(size_t)(crow + r) * DM + c] = a[r];
  }
}

// ---------------------------------------------------------------------------
// K2 fixup_x (r12-exact): x = sum_z P1[z] + bv2 -> xf (f32) + xbf (bf16).
// ---------------------------------------------------------------------------
__global__ __launch_bounds__(256)
void fixup_x(const float* __restrict__ P1, const float* __restrict__ bv2,
             float* __restrict__ xf, ushort* __restrict__ xbf)
{
  const int e = (blockIdx.x * 256 + threadIdx.x) * 4;
  const int c = e % DM;
  float4 s = *(const float4*)(P1 + e);
  #pragma unroll
  for (int z = 1; z < 4; ++z) {
    float4 v = *(const float4*)(P1 + (size_t)z * BATCH * DM + e);
    s.x += v.x; s.y += v.y; s.z += v.z; s.w += v.w;
  }
  float4 bb = *(const float4*)(bv2 + c);
  s.x += bb.x; s.y += bb.y; s.z += bb.z; s.w += bb.w;
  *(float4*)(xf + e) = s;
  uint2 o = { pk2(s.x, s.y), pk2(s.z, s.w) };
  *(uint2*)(xbf + e) = o;
}

// ---------------------------------------------------------------------------
// K3 gemm_g2: A = xbf bf16; B direct from f32 W1 [DM][FF]. Grid (48,8),
// 24 K-steps, depth-2 prefetch. Epi: +b1, exact gelu -> bf16 tbf.
// ---------------------------------------------------------------------------
__global__ __launch_bounds__(256)
void gemm_g2(const ushort* __restrict__ xbf, const float* __restrict__ W1,
             const float* __restrict__ b1, ushort* __restrict__ tbf)
{
  int id = blockIdx.y * 48 + blockIdx.x;
  id = (id & 7) * 48 + (id >> 3);        // XCD swizzle (384 % 8 == 0)
  const int bx = id / 8, by = id % 8;

  const int lane = threadIdx.x & 63, wid = threadIdx.x >> 6;
  const int wr = wid >> 1, wc = wid & 1;
  const int arow = by * 32 + wr * 16 + (lane & 15);
  const int colb = bx * 64 + wc * 32;
  const int kq = (lane >> 4) * 8;

  const ushort* ap = xbf + (size_t)arow * DM + kq;
  const int c0 = colb + (lane & 15), c1 = c0 + 16;
  const float* wrow = W1 + (size_t)kq * FF;

  f32x4 acc0 = (f32x4)(0.0f), acc1 = (f32x4)(0.0f);
  union U { uint4 q; bf16x8 v; };
  U aA, aB;
  float b0A[8], b1A[8], b0B[8], b1B[8];
  aA.q = *(const uint4*)ap;
  aB.q = *(const uint4*)(ap + 32);
  {
    const float* w1r = wrow + (size_t)32 * FF;
    #pragma unroll
    for (int j = 0; j < 8; ++j) {
      b0A[j] = wrow[(size_t)j * FF + c0];
      b1A[j] = wrow[(size_t)j * FF + c1];
      b0B[j] = w1r[(size_t)j * FF + c0];
      b1B[j] = w1r[(size_t)j * FF + c1];
    }
  }

  for (int t = 0; t < 24; t += 2) {
    U aN, aM; float b0n[8], b1n[8], b0m[8], b1m[8];
    const bool m2 = (t + 2) < 24, m3 = (t + 3) < 24;
    if (m2) {
      aN.q = *(const uint4*)(ap + (t + 2) * 32);
      const float* w2r = wrow + (size_t)(t + 2) * 32 * FF;
      #pragma unroll
      for (int j = 0; j < 8; ++j) {
        b0n[j] = w2r[(size_t)j * FF + c0];
        b1n[j] = w2r[(size_t)j * FF + c1];
      }
    }
    if (m3) {
      aM.q = *(const uint4*)(ap + (t + 3) * 32);
      const float* w3r = wrow + (size_t)(t + 3) * 32 * FF;
      #pragma unroll
      for (int j = 0; j < 8; ++j) {
        b0m[j] = w3r[(size_t)j * FF + c0];
        b1m[j] = w3r[(size_t)j * FF + c1];
      }
    }
    union V { unsigned u[4]; bf16x8 v; } bfr0, bfr1;
    #pragma unroll
    for (int j = 0; j < 4; ++j) {
      bfr0.u[j] = pk2(b0A[2*j], b0A[2*j+1]);
      bfr1.u[j] = pk2(b1A[2*j], b1A[2*j+1]);
    }
    acc0 = __builtin_amdgcn_mfma_f32_16x16x32_bf16(aA.v, bfr0.v, acc0, 0, 0, 0);
    acc1 = __builtin_amdgcn_mfma_f32_16x16x32_bf16(aA.v, bfr1.v, acc1, 0, 0, 0);
    #pragma unroll
    for (int j = 0; j < 4; ++j) {
      bfr0.u[j] = pk2(b0B[2*j], b0B[2*j+1]);
      bfr1.u[j] = pk2(b1B[2*j], b1B[2*j+1]);
    }
    acc0 = __builtin_amdgcn_mfma_f32_16x16x32_bf16(aB.v, bfr0.v, acc0, 0, 0, 0);
    acc1 = __builtin_amdgcn_mfma_f32_16x16x32_bf16(aB.v, bfr1.v, acc1, 0, 0, 0);
    if (m2) {
      aA = aN;
      #pragma unroll
      for (int j = 0; j < 8; ++j) { b0A[j] = b0n[j]; b1A[j] = b1n[j]; }
    }
    if (m3) {
      aB = aM;
      #pragma unroll
      for (int j = 0; j < 8; ++j) { b0B[j] = b0m[j]; b1B[j] = b1m[j]; }
    }
  }

  const int crow = by * 32 + wr * 16 + (lane >> 4) * 4;
  #pragma unroll
  for (int nf = 0; nf < 2; ++nf) {
    const int c = colb + nf * 16 + (lane & 15);
    const f32x4 a = nf ? acc1 : acc0;
    #pragma unroll
    for (int r = 0; r < 4; ++r) {
      float v = a[r] + b1[c];
      v = 0.5f * v * (1.0f + erff(v * 0.70710678118654752f));
      tbf[(size_t)(crow + r) * FF + c] = (ushort)bf16rne(v);
    }
  }
}

// ---------------------------------------------------------------------------
// K4 gemm_g3: A = tbf bf16; B direct from f32 W2 [FF][DM]. Split-8, grid
// (12,8,8), 12 K-steps each, depth-2 prefetch. Epi: f32 partial -> P3[z].
// ---------------------------------------------------------------------------
__global__ __launch_bounds__(256)
void gemm_g3(const ushort* __restrict__ tbf, const float* __restrict__ W2,
             float* __restrict__ P3)
{
  int id = blockIdx.y * 12 + blockIdx.x;
  id = (id & 7) * 12 + (id >> 3);        // XCD swizzle (96 % 8 == 0)
  const int bx = id / 8, by = id % 8;

  const int lane = threadIdx.x & 63, wid = threadIdx.x >> 6;
  const int wr = wid >> 1, wc = wid & 1;
  const int arow = by * 32 + wr * 16 + (lane & 15);
  const int colb = bx * 64 + wc * 32;
  const int kq = (lane >> 4) * 8;
  const int kb = blockIdx.z * 384;

  const ushort* ap = tbf + (size_t)arow * FF + kb + kq;
  const int c0 = colb + (lane & 15), c1 = c0 + 16;
  const float* wrow = W2 + (size_t)(kb + kq) * DM;

  f32x4 acc0 = (f32x4)(0.0f), acc1 = (f32x4)(0.0f);
  union U { uint4 q; bf16x8 v; };
  U aA, aB;
  float b0A[8], b1A[8], b0B[8], b1B[8];
  aA.q = *(const uint4*)ap;
  aB.q = *(const uint4*)(ap + 32);
  {
    const float* w1r = wrow + (size_t)32 * DM;
    #pragma unroll
    for (int j = 0; j < 8; ++j) {
      b0A[j] = wrow[(size_t)j * DM + c0];
      b1A[j] = wrow[(size_t)j * DM + c1];
      b0B[j] = w1r[(size_t)j * DM + c0];
      b1B[j] = w1r[(size_t)j * DM + c1];
    }
  }

  for (int t = 0; t < 12; t += 2) {
    U aN, aM; float b0n[8], b1n[8], b0m[8], b1m[8];
    const bool m2 = (t + 2) < 12, m3 = (t + 3) < 12;
    if (m2) {
      aN.q = *(const uint4*)(ap + (t + 2) * 32);
      const float* w2r = wrow + (size_t)(t + 2) * 32 * DM;
      #pragma unroll
      for (int j = 0; j < 8; ++j) {
        b0n[j] = w2r[(size_t)j * DM + c0];
        b1n[j] = w2r[(size_t)j * DM + c1];
      }
    }
    if (m3) {
      aM.q = *(const uint4*)(ap + (t + 3) * 32);
      const float* w3r = wrow + (size_t)(t + 3) * 32 * DM;
      #pragma unroll
      for (int j = 0; j < 8; ++j) {
        b0m[j] = w3r[(size_t)j * DM + c0];
        b1m[j] = w3r[(size_t)j * DM + c1];
      }
    }
    union V { unsigned u[4]; bf16x8 v; } bfr0, bfr1;
    #pragma unroll
    for (int j = 0; j < 4; ++j) {
      bfr0.u[j] = pk2(b0A[2*j], b0A[2*j+1]);
      bfr1.u[j] = pk2(b1A[2*j], b1A[2*j+1]);
    }
    acc0 = __builtin_amdgcn_mfma_f32_16x16x32_bf16(aA.v, bfr0.v, acc0, 0, 0, 0);
    acc1 = __builtin_amdgcn_mfma_f32_16x16x32_bf16(aA.v, bfr1.v, acc1, 0, 0, 0);
    #pragma unroll
    for (int j = 0; j < 4; ++j) {
      bfr0.u[j] = pk2(b0B[2*j], b0B[2*j+1]);
      bfr1.u[j] = pk2(b1B[2*j], b1B[2*j+1]);
    }
    acc0 = __builtin_amdgcn_mfma_f32_16x16x32_bf16(aB.v, bfr0.v, acc0, 0, 0, 0);
    acc1 = __builtin_amdgcn_mfma_f32_16x16x32_bf16(aB.v, bfr1.v, acc1, 0, 0, 0);
    if (m2) {
      aA = aN;
      #pragma unroll
      for (int j = 0; j < 8; ++j) { b0A[j] = b0n[j]; b1A[j] = b1n[j]; }
    }
    if (m3) {
      aB = aM;
      #pragma unroll
      for (int j = 0; j < 8; ++j) { b0B[j] = b0m[j]; b1B[j] = b1m[j]; }
    }
  }

  const int crow = by * 32 + wr * 16 + (lane >> 4) * 4;
  float* dst = P3 + (size_t)blockIdx.z * BATCH * DM;
  #pragma unroll
  for (int nf = 0; nf < 2; ++nf) {
    const int c = colb + nf * 16 + (lane & 15);
    const f32x4 a = nf ? acc1 : acc0;
    #pragma unroll
    for (int r = 0; r < 4; ++r)
      dst[(size_t)(crow + r) * DM + c] = a[r];
  }
}

// ---------------------------------------------------------------------------
// K5 ln_final (r12-exact): y = xf + sum_{z<8} P3[z] + b2, LayerNorm -> out.
// ---------------------------------------------------------------------------
__global__ __launch_bounds__(256)
void ln_final(const float* __restrict__ P3, const float* __restrict__ xf,
              const float* __restrict__ b2, const float* __restrict__ g,
              const float* __restrict__ be, float* __restrict__ out)
{
  const int row = blockIdx.x, tid = threadIdx.x;
  const int lane = tid & 63, wave = tid >> 6;

  float v[3];
  #pragma unroll
  for (int i = 0; i < 3; ++i) {
    const int c = tid + i * 256;
    float s = xf[(size_t)row * DM + c] + b2[c];
    #pragma unroll
    for (int z = 0; z < 8; ++z) s += P3[((size_t)z * BATCH + row) * DM + c];
    v[i] = s;
  }

  __shared__ float red[4];
  float s = v[0] + v[1] + v[2];
  #pragma unroll
  for (int o = 32; o > 0; o >>= 1) s += __shfl_down(s, o);
  if (lane == 0) red[wave] = s;
  __syncthreads();
  const float mu = (red[0] + red[1] + red[2] + red[3]) * (1.0f / 768.0f);
  __syncthreads();
  const float d0 = v[0] - mu, d1 = v[1] - mu, d2 = v[2] - mu;
  float q = d0*d0 + d1*d1 + d2*d2;
  #pragma unroll
  for (int o = 32; o > 0; o >>= 1) q += __shfl_down(q, o);
  if (lane == 0) red[wave] = q;
  __syncthreads();
  const float var = (red[0] + red[1] + red[2] + red[3]) * (1.0f / 768.0f);
  const float inv = rsqrtf(var + 1e-12f);

  float* o = out + (size_t)row * DM;
  o[tid      ] = d0 * inv * g[tid      ] + be[tid      ];
  o[tid + 256] = d1 * inv * g[tid + 256] + be[tid + 256];
  o[tid + 512] = d2 * inv * g[tid + 512] + be[tid + 512];
}

// ---------------------------------------------------------------------------
// 5 kernels (r12 structure, depth-2 prefetch in all GEMMs): G1 -> fixup ->
// G2 -> G3 -> LN. Bit-identical output to r12. ws ~11.2 MB.
// ---------------------------------------------------------------------------
extern "C" void kernel_launch(void* const* d_in, const int* in_sizes, int n_in,
                              void* d_out, int out_size, void* d_ws, size_t ws_size,
                              hipStream_t stream)
{
  const float* im  = (const float*)d_in[0];
  const float* Wv2 = (const float*)d_in[12];
  const float* bv2 = (const float*)d_in[13];
  const float* W1  = (const float*)d_in[14];
  const float* b1  = (const float*)d_in[15];
  const float* W2  = (const float*)d_in[16];
  const float* b2  = (const float*)d_in[17];
  const float* g   = (const float*)d_in[18];
  const float* be  = (const float*)d_in[19];
  float* out = (float*)d_out;

  char* w = (char*)d_ws;
  ushort* xbf = (ushort*)(w);                // 256*768*2   = 393216
  ushort* tbf = (ushort*)(w + 393216);       // 256*3072*2  = 1572864
  float*  xf  = (float*) (w + 1966080);      // 256*768*4   = 786432
  float*  P1  = (float*) (w + 2752512);      // 4*256*768*4 = 3145728
  float*  P3  = (float*) (w + 5898240);      // 8*256*768*4 = 6291456 -> 11.2MB

  // K1: P1[z] = im @ Wv2 slices (direct f32 B, split-4)
  gemm_g1<<<dim3(12, 8, 4), 256, 0, stream>>>(Wv2, im, P1);
  // K2: x = sum P1 + bv2 -> xf, xbf
  fixup_x<<<192, 256, 0, stream>>>(P1, bv2, xf, xbf);
  // K3: tbf = bf16(gelu(x @ W1 + b1))   (direct f32 B)
  gemm_g2<<<dim3(48, 8, 1), 256, 0, stream>>>(xbf, W1, b1, tbf);
  // K4: P3[z] = (t @ W2) K-slices       (direct f32 B, split-8)
  gemm_g3<<<dim3(12, 8, 8), 256, 0, stream>>>(tbf, W2, P3);
  // K5: LN(xf + sum P3 + b2) -> out
  ln_final<<<BATCH, 256, 0, stream>>>(P3, xf, b2, g, be, out);
}